// Round 11
// baseline (5662.974 us; speedup 1.0000x reference)
//
#include <hip/hip_runtime.h>

typedef unsigned short u16;
typedef unsigned int u32;
typedef __attribute__((ext_vector_type(8))) short short8v;
typedef __attribute__((ext_vector_type(4))) float f32x4;
typedef __attribute__((ext_vector_type(4))) unsigned int u32x4;
typedef __attribute__((ext_vector_type(2))) _Float16 f16x2;

#define NB 64
#define NT 256
#define NM 512
#define NH 256

#define K2 2.8853900817779268f   // 2*log2(e)
#define LOG2E 1.4426950408889634f

__device__ __forceinline__ float bf2f(u16 u) {
  union { unsigned i; float f; } c; c.i = ((unsigned)u) << 16; return c.f;
}
__device__ __forceinline__ u16 f2bf(float f) {
  union { float fv; unsigned i; } c; c.fv = f;
  unsigned i = c.i;
  return (u16)((i + 0x7fffu + ((i >> 16) & 1u)) >> 16);
}
__device__ __forceinline__ float bits2f(u32 u) {
  union { unsigned i; float f; } c; c.i = u; return c.f;
}
__device__ __forceinline__ f16x2 u2h2(u32 u) {
  union { u32 i; f16x2 h; } c; c.i = u; return c.h;
}
// pack two floats to f16x2 bits (cvt_pkrtz returns __fp16 vec; bit-cast via union)
__device__ __forceinline__ u32 pkrtz(float a, float b) {
  auto h = __builtin_amdgcn_cvt_pkrtz(a, b);
  union { decltype(h) v; u32 i; } c; c.v = h; return c.i;
}
#if __has_builtin(__builtin_amdgcn_fdot2)
__device__ __forceinline__ float FDOT2(f16x2 a, f16x2 b, float c) {
  return __builtin_amdgcn_fdot2(a, b, c, false);
}
#else
__device__ __forceinline__ float FDOT2(f16x2 a, f16x2 b, float c) {
  c = fmaf((float)a.x, (float)b.x, c);
  return fmaf((float)a.y, (float)b.y, c);
}
#endif
__device__ __forceinline__ float tanh_fast(float x) {
  return 1.0f - 2.0f * __builtin_amdgcn_rcpf(1.0f + __builtin_amdgcn_exp2f(K2 * x));
}
__device__ __forceinline__ float sigmoid_fast(float x) {
  return __builtin_amdgcn_rcpf(1.0f + __builtin_amdgcn_exp2f(-LOG2E * x));
}

__global__ void convert_f32_bf16(const float* __restrict__ in, u16* __restrict__ out, int n) {
  int i = blockIdx.x * blockDim.x + threadIdx.x;
  if (i < n) out[i] = f2bf(in[i]);
}

// wdt2[k2*512+m] = pack_f16(Wd_w[m][2k2], Wd_w[m][2k2+1]);  k2 in [0,256)
__global__ __launch_bounds__(256) void pack_wd2(const float* __restrict__ in,
                                                u32* __restrict__ out) {
  int i = blockIdx.x * 256 + threadIdx.x;   // 131072
  int k2 = i >> 9, m = i & 511;
  out[i] = pkrtz(in[m * 512 + 2 * k2], in[m * 512 + 2 * k2 + 1]);
}
// whht2[k2*1024+r] = pack_f16(Whh[r][2k2], Whh[r][2k2+1]);  k2 in [0,128)
__global__ __launch_bounds__(256) void pack_whh2(const float* __restrict__ in,
                                                 u32* __restrict__ out) {
  int i = blockIdx.x * 256 + threadIdx.x;   // 131072
  int k2 = i >> 10, r = i & 1023;
  out[i] = pkrtz(in[r * 256 + 2 * k2], in[r * 256 + 2 * k2 + 1]);
}

// y1' = K2 * enc @ Ud^T  (bf16 out, prescaled for exp2-based tanh)
__global__ __launch_bounds__(256) void gemm_y1(const u16* __restrict__ A,
                                               const u16* __restrict__ Bm,
                                               u16* __restrict__ C) {
  const int w = threadIdx.x >> 6;
  const int l = threadIdx.x & 63;
  const int kg = l >> 4;
  const int r16 = l & 15;
  const int rowbase = blockIdx.x * 64 + w * 16;
  const int colbase = blockIdx.y * 64;
  const u16* ap = A + (size_t)(rowbase + r16) * 512 + kg * 8;
  f32x4 acc0 = {0,0,0,0}, acc1 = {0,0,0,0}, acc2 = {0,0,0,0}, acc3 = {0,0,0,0};
  for (int k = 0; k < 512; k += 32) {
    short8v af = *(const short8v*)(ap + k);
    const u16* bp = Bm + (size_t)(colbase + r16) * 512 + kg * 8 + k;
    short8v b0 = *(const short8v*)(bp);
    short8v b1 = *(const short8v*)(bp + 16 * 512);
    short8v b2 = *(const short8v*)(bp + 32 * 512);
    short8v b3 = *(const short8v*)(bp + 48 * 512);
    acc0 = __builtin_amdgcn_mfma_f32_16x16x32_bf16(af, b0, acc0, 0, 0, 0);
    acc1 = __builtin_amdgcn_mfma_f32_16x16x32_bf16(af, b1, acc1, 0, 0, 0);
    acc2 = __builtin_amdgcn_mfma_f32_16x16x32_bf16(af, b2, acc2, 0, 0, 0);
    acc3 = __builtin_amdgcn_mfma_f32_16x16x32_bf16(af, b3, acc3, 0, 0, 0);
  }
  #pragma unroll
  for (int j = 0; j < 4; ++j) {
    int r = rowbase + (l >> 4) * 4 + j;
    C[(size_t)r * 512 + colbase +  0 + r16] = f2bf(K2 * acc0[j]);
    C[(size_t)r * 512 + colbase + 16 + r16] = f2bf(K2 * acc1[j]);
    C[(size_t)r * 512 + colbase + 32 + r16] = f2bf(K2 * acc2[j]);
    C[(size_t)r * 512 + colbase + 48 + r16] = f2bf(K2 * acc3[j]);
  }
}

// w_enc[b,te] = sum_m enc[b,te,m] * wtw[m]
__global__ __launch_bounds__(256) void wenc_kernel(const u16* __restrict__ encbf,
                                                   const float* __restrict__ wtw,
                                                   float* __restrict__ gwenc) {
  int b = blockIdx.x, te = threadIdx.x;
  const u16* ep = encbf + ((size_t)(b * NT + te)) * NM;
  float a = 0.0f;
  for (int c8 = 0; c8 < 64; ++c8) {
    short8v v = *(const short8v*)(ep + c8 * 8);
    #pragma unroll
    for (int jj = 0; jj < 8; ++jj) a = fmaf(bf2f((u16)v[jj]), wtw[c8 * 8 + jj], a);
  }
  gwenc[b * NT + te] = a;
}

// out[b,m] = sum_te betaAcc[b,te] * enc[b,te,m]
__global__ __launch_bounds__(512) void bsum_kernel(const u16* __restrict__ encbf,
                                                   const float* __restrict__ gbeta,
                                                   float* __restrict__ out) {
  __shared__ float bl[NT];
  int b = blockIdx.x, m = threadIdx.x;
  if (m < 256) bl[m] = gbeta[b * NT + m];
  __syncthreads();
  const u16* ep = encbf + (size_t)b * NT * NM + m;
  float a = 0.0f;
  #pragma unroll 8
  for (int te = 0; te < NT; ++te)
    a = fmaf(bf2f(ep[(size_t)te * NM]), bl[te], a);
  out[b * NM + m] = a;
}

// ONE workgroup per batch. No inter-WG communication.
// waves_per_eu(4,4): 4 waves/SIMD -> 128 VGPRs/thread (4x128 = full file),
// required so the 64-VGPR y1 tile stays in registers (VGPR=64 in r8/r10 = spill).
__attribute__((amdgpu_waves_per_eu(4, 4)))
__global__ void __launch_bounds__(1024) attn_scan(
    const u16* __restrict__ y1bf,    // [B,T,M] prescaled by K2
    const u32* __restrict__ wdt2,    // [256 k2][512 m] f16-pairs along k of (d;s)
    const u32* __restrict__ whht2,   // [128 k2][1024 r] f16-pairs along k of d
    const float* __restrict__ Wd_b,  // [512]
    const float* __restrict__ vd,    // [512]
    const float* __restrict__ wtw,   // [513]
    const float* __restrict__ wtb,   // [1]
    const float* __restrict__ Wih,   // [1024]
    const float* __restrict__ bih,   // [1024]
    const float* __restrict__ bhh,   // [1024]
    const float* __restrict__ yin,   // [B,T]
    const float* __restrict__ gwenc, // [B,256]
    float* __restrict__ gbeta)       // [B,256] sum_t beta
{
  extern __shared__ char ldsraw[];
  float* gp  = (float*)ldsraw;            // [8][1024] Whh partials (32 KiB)
  float* x1p = (float*)(ldsraw + 32768);  // [8][512] Wd partials (16 KiB)

  __shared__ float x1_l2[NM];   // [j][m>>3]: idx (m&7)*64+(m>>3) holds x1[m]
  __shared__ u32 pk_ds[256];    // f16 pairs: [0..127]=d, [128..255]=s
  __shared__ float l_sl[NT];
  __shared__ float wih_l[1024];
  __shared__ float bb_l[1024];
  __shared__ float wenc_l[NT];
  __shared__ float yin_l[NT];
  __shared__ float wdb_l[NM];

  const int tid = threadIdx.x;
  const int b = blockIdx.x;
  const int w = tid >> 6, l = tid & 63;

  // ---- one-time init ----
  wih_l[tid] = Wih[tid];
  bb_l[tid] = bih[tid] + bhh[tid];
  if (tid < 256) {
    wenc_l[tid] = gwenc[b * NT + tid];
    yin_l[tid] = yin[b * NT + tid];
  }
  if (tid < 512) {
    float wb = Wd_b[tid];
    wdb_l[tid] = wb;
    x1_l2[(tid & 7) * 64 + (tid >> 3)] = K2 * wb;  // x1_0 = Wd·0 + b
  }
  for (int i = tid; i < 8192; i += 1024) gp[i] = 0.0f;  // Whh·d_{-1} = 0

  float vr[8];
  #pragma unroll
  for (int j = 0; j < 8; ++j) vr[j] = vd[l * 8 + j];
  float sv = 0.0f;
  #pragma unroll
  for (int j = 0; j < 8; ++j) sv += vr[j];
  #pragma unroll
  for (int off = 32; off > 0; off >>= 1) sv += __shfl_xor(sv, off, 64);
  const float Svd = sv;
  const float wtw512 = wtw[NM];
  const float wtb0 = wtb[0];

  // ---- persistent y1 tile: wave w owns te = w*16+i; lane l owns m = l*8..+7 ----
  u32x4 y1R[16];
  {
    const u16* ybase = y1bf + ((size_t)(b * NT + w * 16) << 9) + l * 8;
    #pragma unroll
    for (int i = 0; i < 16; ++i)
      y1R[i] = *(const u32x4*)(ybase + (size_t)i * 512);
  }
  asm volatile("" : "+v"(y1R[0]), "+v"(y1R[1]), "+v"(y1R[2]), "+v"(y1R[3]),
                    "+v"(y1R[4]), "+v"(y1R[5]), "+v"(y1R[6]), "+v"(y1R[7]),
                    "+v"(y1R[8]), "+v"(y1R[9]), "+v"(y1R[10]), "+v"(y1R[11]),
                    "+v"(y1R[12]), "+v"(y1R[13]), "+v"(y1R[14]), "+v"(y1R[15]));

  float s_reg = 0.0f;  // threads 0-255: cell state c[h]
  float bacc = 0.0f;   // waves 4-7: sum_t beta[(w-4)*64+l]
  __syncthreads();

  #pragma unroll 1
  for (int t = 0; t < NT; ++t) {
    // ---- B1: l_it (all 16 waves, 16 te each) ----
    {
      float xr[8];
      #pragma unroll
      for (int j = 0; j < 8; ++j) xr[j] = x1_l2[j * 64 + l];
      float lout = 0.0f;
      #pragma unroll
      for (int i = 0; i < 16; ++i) {
        float a = 0.0f;
        #pragma unroll
        for (int n = 0; n < 4; ++n) {
          u32 v = y1R[i][n];
          float e0 = __builtin_amdgcn_exp2f(xr[2 * n] + bits2f(v << 16));
          a = fmaf(vr[2 * n], __builtin_amdgcn_rcpf(1.0f + e0), a);
          float e1 = __builtin_amdgcn_exp2f(xr[2 * n + 1] + bits2f(v & 0xffff0000u));
          a = fmaf(vr[2 * n + 1], __builtin_amdgcn_rcpf(1.0f + e1), a);
        }
        #pragma unroll
        for (int off = 32; off > 0; off >>= 1) a += __shfl_xor(a, off, 64);
        if (l == i) lout = Svd - 2.0f * a;
      }
      if (l < 16) l_sl[w * 16 + l] = lout;
    }
    __syncthreads();  // (1) l_sl ready

    // ---- B2+B3: waves 0-7 redundant softmax, then role split ----
    if (w < 8) {
      float v0 = l_sl[l], v1 = l_sl[64 + l], v2 = l_sl[128 + l], v3 = l_sl[192 + l];
      float mx = fmaxf(fmaxf(v0, v1), fmaxf(v2, v3));
      #pragma unroll
      for (int off = 32; off > 0; off >>= 1) mx = fmaxf(mx, __shfl_xor(mx, off, 64));
      float e0 = __builtin_amdgcn_exp2f((v0 - mx) * LOG2E);
      float e1 = __builtin_amdgcn_exp2f((v1 - mx) * LOG2E);
      float e2 = __builtin_amdgcn_exp2f((v2 - mx) * LOG2E);
      float e3 = __builtin_amdgcn_exp2f((v3 - mx) * LOG2E);
      float sq = (e0 + e1) + (e2 + e3);
      float nq = fmaf(e0, wenc_l[l], fmaf(e1, wenc_l[64 + l],
                 fmaf(e2, wenc_l[128 + l], e3 * wenc_l[192 + l])));
      #pragma unroll
      for (int off = 32; off > 0; off >>= 1) {
        sq += __shfl_xor(sq, off, 64);
        nq += __shfl_xor(nq, off, 64);
      }
      float rden = __builtin_amdgcn_rcpf(sq);
      float yt = nq * rden + wtw512 * yin_l[t] + wtb0;

      if (tid < 256) {
        // gates+cell (threads 0-255)
        int h = tid;
        float g0 = 0.0f, g1 = 0.0f, g2 = 0.0f, g3 = 0.0f;
        #pragma unroll
        for (int s = 0; s < 8; ++s) {
          const float* gs = gp + s * 1024 + h;
          g0 += gs[0]; g1 += gs[256]; g2 += gs[512]; g3 += gs[768];
        }
        float gi = sigmoid_fast(g0 + yt * wih_l[h]       + bb_l[h]);
        float gf = sigmoid_fast(g1 + yt * wih_l[256 + h] + bb_l[256 + h]);
        float gg = tanh_fast   (g2 + yt * wih_l[512 + h] + bb_l[512 + h]);
        float go = sigmoid_fast(g3 + yt * wih_l[768 + h] + bb_l[768 + h]);
        float sn = gf * s_reg + gi * gg;
        s_reg = sn;
        float dn = go * tanh_fast(sn);
        float dn1 = __shfl_xor(dn, 1, 64);
        float sn1 = __shfl_xor(sn, 1, 64);
        if ((h & 1) == 0) {
          pk_ds[h >> 1] = pkrtz(dn, dn1);
          pk_ds[128 + (h >> 1)] = pkrtz(sn, sn1);
        }
      } else {
        // beta accumulation (waves 4-7): own e for te = (w-4)*64 + l
        float e_own = (w == 4) ? e0 : (w == 5) ? e1 : (w == 6) ? e2 : e3;
        bacc = fmaf(e_own, rden, bacc);
      }
    }
    __syncthreads();  // (3) pk_ds ready

    // ---- B4: waves 0-7: Wd GEMV (x1 for t+1) | waves 8-15: Whh GEMV ----
    if (w < 8) {
      float a0 = 0, a1 = 0, a2 = 0, a3 = 0, a4 = 0, a5 = 0, a6 = 0, a7 = 0;
      const u32* base = wdt2 + (size_t)(w * 32) * 512 + l * 8;
      const u32* pk = (const u32*)pk_ds + w * 32;
      #pragma unroll 8
      for (int kk = 0; kk < 32; ++kk) {
        u32x4 W0 = *(const u32x4*)(base + (size_t)kk * 512);
        u32x4 W1 = *(const u32x4*)(base + (size_t)kk * 512 + 4);
        f16x2 dk = u2h2(pk[kk]);
        a0 = FDOT2(u2h2(W0[0]), dk, a0);
        a1 = FDOT2(u2h2(W0[1]), dk, a1);
        a2 = FDOT2(u2h2(W0[2]), dk, a2);
        a3 = FDOT2(u2h2(W0[3]), dk, a3);
        a4 = FDOT2(u2h2(W1[0]), dk, a4);
        a5 = FDOT2(u2h2(W1[1]), dk, a5);
        a6 = FDOT2(u2h2(W1[2]), dk, a6);
        a7 = FDOT2(u2h2(W1[3]), dk, a7);
      }
      f32x4 o0 = {a0, a1, a2, a3}, o1 = {a4, a5, a6, a7};
      *(f32x4*)(x1p + w * 512 + l * 8) = o0;
      *(f32x4*)(x1p + w * 512 + l * 8 + 4) = o1;
    } else {
      const int sl = w - 8;
      float a0 = 0, a1 = 0, a2 = 0, a3 = 0, a4 = 0, a5 = 0, a6 = 0, a7 = 0;
      float c0 = 0, c1 = 0, c2 = 0, c3 = 0, c4 = 0, c5 = 0, c6 = 0, c7 = 0;
      const u32* base = whht2 + (size_t)(sl * 16) * 1024 + l * 8;
      const u32* pk = (const u32*)pk_ds + sl * 16;
      #pragma unroll 4
      for (int kk = 0; kk < 16; ++kk) {
        u32x4 Wa0 = *(const u32x4*)(base + (size_t)kk * 1024);
        u32x4 Wa1 = *(const u32x4*)(base + (size_t)kk * 1024 + 4);
        u32x4 Wc0 = *(const u32x4*)(base + (size_t)kk * 1024 + 512);
        u32x4 Wc1 = *(const u32x4*)(base + (size_t)kk * 1024 + 516);
        f16x2 dk = u2h2(pk[kk]);
        a0 = FDOT2(u2h2(Wa0[0]), dk, a0);
        a1 = FDOT2(u2h2(Wa0[1]), dk, a1);
        a2 = FDOT2(u2h2(Wa0[2]), dk, a2);
        a3 = FDOT2(u2h2(Wa0[3]), dk, a3);
        a4 = FDOT2(u2h2(Wa1[0]), dk, a4);
        a5 = FDOT2(u2h2(Wa1[1]), dk, a5);
        a6 = FDOT2(u2h2(Wa1[2]), dk, a6);
        a7 = FDOT2(u2h2(Wa1[3]), dk, a7);
        c0 = FDOT2(u2h2(Wc0[0]), dk, c0);
        c1 = FDOT2(u2h2(Wc0[1]), dk, c1);
        c2 = FDOT2(u2h2(Wc0[2]), dk, c2);
        c3 = FDOT2(u2h2(Wc0[3]), dk, c3);
        c4 = FDOT2(u2h2(Wc1[0]), dk, c4);
        c5 = FDOT2(u2h2(Wc1[1]), dk, c5);
        c6 = FDOT2(u2h2(Wc1[2]), dk, c6);
        c7 = FDOT2(u2h2(Wc1[3]), dk, c7);
      }
      f32x4 o0 = {a0, a1, a2, a3}, o1 = {a4, a5, a6, a7};
      f32x4 o2 = {c0, c1, c2, c3}, o3 = {c4, c5, c6, c7};
      *(f32x4*)(gp + sl * 1024 + l * 8) = o0;
      *(f32x4*)(gp + sl * 1024 + l * 8 + 4) = o1;
      *(f32x4*)(gp + sl * 1024 + 512 + l * 8) = o2;
      *(f32x4*)(gp + sl * 1024 + 512 + l * 8 + 4) = o3;
    }
    __syncthreads();  // (4) x1p, gp ready

    // ---- B5: assemble x1 for t+1 (threads 0-511) ----
    if (tid < 512) {
      int m = tid;
      float s = x1p[m] + x1p[512 + m] + x1p[1024 + m] + x1p[1536 + m]
              + x1p[2048 + m] + x1p[2560 + m] + x1p[3072 + m] + x1p[3584 + m];
      x1_l2[(m & 7) * 64 + (m >> 3)] = K2 * (wdb_l[m] + s);
    }
    __syncthreads();  // (5) x1_l2 ready
  }

  if (w >= 4 && w < 8) gbeta[b * NT + (w - 4) * 64 + l] = bacc;
}

extern "C" void kernel_launch(void* const* d_in, const int* in_sizes, int n_in,
                              void* d_out, int out_size, void* d_ws, size_t ws_size,
                              hipStream_t stream) {
  const float* enc  = (const float*)d_in[0];
  const float* yin  = (const float*)d_in[1];
  const float* Wd_w = (const float*)d_in[2];
  const float* Wd_b = (const float*)d_in[3];
  const float* Ud_w = (const float*)d_in[4];
  const float* vd_w = (const float*)d_in[5];
  const float* wt_w = (const float*)d_in[6];
  const float* wt_b = (const float*)d_in[7];
  const float* Wih  = (const float*)d_in[8];
  const float* Whh  = (const float*)d_in[9];
  const float* bih  = (const float*)d_in[10];
  const float* bhh  = (const float*)d_in[11];

  char* ws = (char*)d_ws;
  u16*   y1bf   = (u16*)(ws);                     // 16,777,216
  u16*   encbf  = (u16*)(ws + 16777216);          // 16,777,216
  u16*   udbf   = (u16*)(ws + 33554432);          // 524,288
  u32*   wdt2   = (u32*)(ws + 34078720);          // 524,288
  u32*   whht2  = (u32*)(ws + 34603008);          // 524,288
  float* gwenc  = (float*)(ws + 35127296);        // 65,536
  float* gbeta  = (float*)(ws + 35192832);        // 65,536

  convert_f32_bf16<<<8388608 / 256, 256, 0, stream>>>(enc, encbf, 8388608);
  convert_f32_bf16<<<262144 / 256, 256, 0, stream>>>(Ud_w, udbf, 262144);
  pack_wd2<<<512, 256, 0, stream>>>(Wd_w, wdt2);
  pack_whh2<<<512, 256, 0, stream>>>(Whh, whht2);
  gemm_y1<<<dim3(256, 8), 256, 0, stream>>>(encbf, udbf, y1bf);
  wenc_kernel<<<64, 256, 0, stream>>>(encbf, wt_w, gwenc);

  hipFuncSetAttribute((const void*)attn_scan,
                      hipFuncAttributeMaxDynamicSharedMemorySize, 49152);
  attn_scan<<<64, 1024, 49152, stream>>>(y1bf, wdt2, whht2, Wd_b, vd_w,
                                         wt_w, wt_b, Wih, bih, bhh, yin, gwenc,
                                         gbeta);
  bsum_kernel<<<64, 512, 0, stream>>>(encbf, gbeta, (float*)d_out);
}

// Round 12
// 5216.709 us; speedup vs baseline: 1.0855x; 1.0855x over previous
//
#include <hip/hip_runtime.h>

typedef unsigned short u16;
typedef unsigned int u32;
typedef __attribute__((ext_vector_type(8))) short short8v;
typedef __attribute__((ext_vector_type(4))) float f32x4;
typedef __attribute__((ext_vector_type(4))) unsigned int u32x4;
typedef __attribute__((ext_vector_type(2))) _Float16 f16x2;

#define NB 64
#define NT 256
#define NM 512
#define NH 256

#define K2 2.8853900817779268f   // 2*log2(e)
#define LOG2E 1.4426950408889634f

__device__ __forceinline__ float bf2f(u16 u) {
  union { unsigned i; float f; } c; c.i = ((unsigned)u) << 16; return c.f;
}
__device__ __forceinline__ u16 f2bf(float f) {
  union { float fv; unsigned i; } c; c.fv = f;
  unsigned i = c.i;
  return (u16)((i + 0x7fffu + ((i >> 16) & 1u)) >> 16);
}
__device__ __forceinline__ float bits2f(u32 u) {
  union { unsigned i; float f; } c; c.i = u; return c.f;
}
__device__ __forceinline__ f16x2 u2h2(u32 u) {
  union { u32 i; f16x2 h; } c; c.i = u; return c.h;
}
// pack two floats to f16x2 bits (cvt_pkrtz returns __fp16 vec; bit-cast via union)
__device__ __forceinline__ u32 pkrtz(float a, float b) {
  auto h = __builtin_amdgcn_cvt_pkrtz(a, b);
  union { decltype(h) v; u32 i; } c; c.v = h; return c.i;
}
// unpack one f16 of a pair to float
__device__ __forceinline__ float unpk(u32 v, int hi) {
  f16x2 h = u2h2(v);
  return hi ? (float)h.y : (float)h.x;
}
#if __has_builtin(__builtin_amdgcn_fdot2)
__device__ __forceinline__ float FDOT2(f16x2 a, f16x2 b, float c) {
  return __builtin_amdgcn_fdot2(a, b, c, false);
}
#else
__device__ __forceinline__ float FDOT2(f16x2 a, f16x2 b, float c) {
  c = fmaf((float)a.x, (float)b.x, c);
  return fmaf((float)a.y, (float)b.y, c);
}
#endif
__device__ __forceinline__ float tanh_fast(float x) {
  return 1.0f - 2.0f * __builtin_amdgcn_rcpf(1.0f + __builtin_amdgcn_exp2f(K2 * x));
}
__device__ __forceinline__ float sigmoid_fast(float x) {
  return __builtin_amdgcn_rcpf(1.0f + __builtin_amdgcn_exp2f(-LOG2E * x));
}

__global__ void convert_f32_bf16(const float* __restrict__ in, u16* __restrict__ out, int n) {
  int i = blockIdx.x * blockDim.x + threadIdx.x;
  if (i < n) out[i] = f2bf(in[i]);
}

// wdt2[k2*512+m] = pack_f16(Wd_w[m][2k2], Wd_w[m][2k2+1]);  k2 in [0,256)
__global__ __launch_bounds__(256) void pack_wd2(const float* __restrict__ in,
                                                u32* __restrict__ out) {
  int i = blockIdx.x * 256 + threadIdx.x;   // 131072
  int k2 = i >> 9, m = i & 511;
  out[i] = pkrtz(in[m * 512 + 2 * k2], in[m * 512 + 2 * k2 + 1]);
}
// whht2[k2*1024+r] = pack_f16(Whh[r][2k2], Whh[r][2k2+1]);  k2 in [0,128)
__global__ __launch_bounds__(256) void pack_whh2(const float* __restrict__ in,
                                                 u32* __restrict__ out) {
  int i = blockIdx.x * 256 + threadIdx.x;   // 131072
  int k2 = i >> 10, r = i & 1023;
  out[i] = pkrtz(in[r * 256 + 2 * k2], in[r * 256 + 2 * k2 + 1]);
}

// y1' = K2 * enc @ Ud^T  (bf16 out, prescaled for exp2-based tanh)
__global__ __launch_bounds__(256) void gemm_y1(const u16* __restrict__ A,
                                               const u16* __restrict__ Bm,
                                               u16* __restrict__ C) {
  const int w = threadIdx.x >> 6;
  const int l = threadIdx.x & 63;
  const int kg = l >> 4;
  const int r16 = l & 15;
  const int rowbase = blockIdx.x * 64 + w * 16;
  const int colbase = blockIdx.y * 64;
  const u16* ap = A + (size_t)(rowbase + r16) * 512 + kg * 8;
  f32x4 acc0 = {0,0,0,0}, acc1 = {0,0,0,0}, acc2 = {0,0,0,0}, acc3 = {0,0,0,0};
  for (int k = 0; k < 512; k += 32) {
    short8v af = *(const short8v*)(ap + k);
    const u16* bp = Bm + (size_t)(colbase + r16) * 512 + kg * 8 + k;
    short8v b0 = *(const short8v*)(bp);
    short8v b1 = *(const short8v*)(bp + 16 * 512);
    short8v b2 = *(const short8v*)(bp + 32 * 512);
    short8v b3 = *(const short8v*)(bp + 48 * 512);
    acc0 = __builtin_amdgcn_mfma_f32_16x16x32_bf16(af, b0, acc0, 0, 0, 0);
    acc1 = __builtin_amdgcn_mfma_f32_16x16x32_bf16(af, b1, acc1, 0, 0, 0);
    acc2 = __builtin_amdgcn_mfma_f32_16x16x32_bf16(af, b2, acc2, 0, 0, 0);
    acc3 = __builtin_amdgcn_mfma_f32_16x16x32_bf16(af, b3, acc3, 0, 0, 0);
  }
  #pragma unroll
  for (int j = 0; j < 4; ++j) {
    int r = rowbase + (l >> 4) * 4 + j;
    C[(size_t)r * 512 + colbase +  0 + r16] = f2bf(K2 * acc0[j]);
    C[(size_t)r * 512 + colbase + 16 + r16] = f2bf(K2 * acc1[j]);
    C[(size_t)r * 512 + colbase + 32 + r16] = f2bf(K2 * acc2[j]);
    C[(size_t)r * 512 + colbase + 48 + r16] = f2bf(K2 * acc3[j]);
  }
}

// w_enc[b,te] = sum_m enc[b,te,m] * wtw[m]
__global__ __launch_bounds__(256) void wenc_kernel(const u16* __restrict__ encbf,
                                                   const float* __restrict__ wtw,
                                                   float* __restrict__ gwenc) {
  int b = blockIdx.x, te = threadIdx.x;
  const u16* ep = encbf + ((size_t)(b * NT + te)) * NM;
  float a = 0.0f;
  for (int c8 = 0; c8 < 64; ++c8) {
    short8v v = *(const short8v*)(ep + c8 * 8);
    #pragma unroll
    for (int jj = 0; jj < 8; ++jj) a = fmaf(bf2f((u16)v[jj]), wtw[c8 * 8 + jj], a);
  }
  gwenc[b * NT + te] = a;
}

// out[b,m] = sum_te betaAcc[b,te] * enc[b,te,m]
__global__ __launch_bounds__(512) void bsum_kernel(const u16* __restrict__ encbf,
                                                   const float* __restrict__ gbeta,
                                                   float* __restrict__ out) {
  __shared__ float bl[NT];
  int b = blockIdx.x, m = threadIdx.x;
  if (m < 256) bl[m] = gbeta[b * NT + m];
  __syncthreads();
  const u16* ep = encbf + (size_t)b * NT * NM + m;
  float a = 0.0f;
  #pragma unroll 8
  for (int te = 0; te < NT; ++te)
    a = fmaf(bf2f(ep[(size_t)te * NM]), bl[te], a);
  out[b * NM + m] = a;
}

// ONE workgroup per batch. No inter-WG communication.
// LDS total 104 KiB > 80 KiB -> only 1 WG/CU fits -> compiler's best occupancy
// is 4 waves/SIMD -> VGPR budget 128 (launch_bounds 2nd arg reinforces).
// y1 tile: 12 te/wave in regs (48 VGPR) + 4 te/wave in LDS (64 KiB).
__global__ void __launch_bounds__(1024, 4) attn_scan(
    const u16* __restrict__ y1bf,    // [B,T,M] prescaled by K2
    const u32* __restrict__ wdt2,    // [256 k2][512 m] f16-pairs along k of (d;s)
    const u32* __restrict__ whht2,   // [128 k2][1024 r] f16-pairs along k of d
    const float* __restrict__ Wd_b,  // [512]
    const float* __restrict__ vd,    // [512]
    const float* __restrict__ wtw,   // [513]
    const float* __restrict__ wtb,   // [1]
    const float* __restrict__ Wih,   // [1024]
    const float* __restrict__ bih,   // [1024]
    const float* __restrict__ bhh,   // [1024]
    const float* __restrict__ yin,   // [B,T]
    const float* __restrict__ gwenc, // [B,256]
    float* __restrict__ gbeta)       // [B,256] sum_t beta
{
  extern __shared__ char ldsraw[];
  u16* y1L  = (u16*)ldsraw;                // [64 rows][512] bf16, 64 KiB
  u32* gph  = (u32*)(ldsraw + 65536);      // [8][512] f16-pair Whh partials, 16 KiB
  u32* x1ph = (u32*)(ldsraw + 81920);      // [8][256] f16-pair Wd partials, 8 KiB

  __shared__ float x1_l2[NM];   // [j][m>>3]: idx (m&7)*64+(m>>3) holds x1[m]
  __shared__ u32 pk_ds[256];    // f16 pairs: [0..127]=d, [128..255]=s
  __shared__ float l_sl[NT];
  __shared__ float wih_l[1024];
  __shared__ float bb_l[1024];
  __shared__ float wenc_l[NT];
  __shared__ float yin_l[NT];
  __shared__ float wdb_l[NM];

  const int tid = threadIdx.x;
  const int b = blockIdx.x;
  const int w = tid >> 6, l = tid & 63;

  // ---- one-time init ----
  wih_l[tid] = Wih[tid];
  bb_l[tid] = bih[tid] + bhh[tid];
  if (tid < 256) {
    wenc_l[tid] = gwenc[b * NT + tid];
    yin_l[tid] = yin[b * NT + tid];
  }
  if (tid < 512) {
    float wb = Wd_b[tid];
    wdb_l[tid] = wb;
    x1_l2[(tid & 7) * 64 + (tid >> 3)] = K2 * wb;  // x1_0 = Wd·0 + b
  }
  for (int i = tid; i < 4096; i += 1024) gph[i] = 0;  // Whh·d_{-1} = 0 (f16 0x0)

  float vr[8];
  #pragma unroll
  for (int j = 0; j < 8; ++j) vr[j] = vd[l * 8 + j];
  float sv = 0.0f;
  #pragma unroll
  for (int j = 0; j < 8; ++j) sv += vr[j];
  #pragma unroll
  for (int off = 32; off > 0; off >>= 1) sv += __shfl_xor(sv, off, 64);
  const float Svd = sv;
  const float wtw512 = wtw[NM];
  const float wtb0 = wtb[0];

  // ---- y1 tile: wave w owns te = w*16+i. i<12 -> regs; i>=12 -> LDS ----
  u32x4 y1R[12];
  {
    const u16* ybase = y1bf + ((size_t)(b * NT + w * 16) << 9) + l * 8;
    #pragma unroll
    for (int i = 0; i < 12; ++i)
      y1R[i] = *(const u32x4*)(ybase + (size_t)i * 512);
    #pragma unroll
    for (int i = 12; i < 16; ++i) {
      int row = w * 4 + (i - 12);
      *(u32x4*)(y1L + row * 512 + l * 8) = *(const u32x4*)(ybase + (size_t)i * 512);
    }
  }
  asm volatile("" : "+v"(y1R[0]), "+v"(y1R[1]), "+v"(y1R[2]), "+v"(y1R[3]),
                    "+v"(y1R[4]), "+v"(y1R[5]), "+v"(y1R[6]), "+v"(y1R[7]),
                    "+v"(y1R[8]), "+v"(y1R[9]), "+v"(y1R[10]), "+v"(y1R[11]));

  float s_reg = 0.0f;  // threads 0-255: cell state c[h]
  float bacc = 0.0f;   // waves 4-7: sum_t beta[(w-4)*64+l]
  __syncthreads();

  #pragma unroll 1
  for (int t = 0; t < NT; ++t) {
    // ---- B1: l_it (all 16 waves, 16 te each) ----
    {
      float xr[8];
      #pragma unroll
      for (int j = 0; j < 8; ++j) xr[j] = x1_l2[j * 64 + l];
      float lout = 0.0f;
      #pragma unroll
      for (int i = 0; i < 16; ++i) {
        u32x4 V = (i < 12) ? y1R[i]
                : *(const u32x4*)(y1L + (w * 4 + (i - 12)) * 512 + l * 8);
        float a = 0.0f;
        #pragma unroll
        for (int n = 0; n < 4; ++n) {
          u32 v = V[n];
          float e0 = __builtin_amdgcn_exp2f(xr[2 * n] + bits2f(v << 16));
          a = fmaf(vr[2 * n], __builtin_amdgcn_rcpf(1.0f + e0), a);
          float e1 = __builtin_amdgcn_exp2f(xr[2 * n + 1] + bits2f(v & 0xffff0000u));
          a = fmaf(vr[2 * n + 1], __builtin_amdgcn_rcpf(1.0f + e1), a);
        }
        #pragma unroll
        for (int off = 32; off > 0; off >>= 1) a += __shfl_xor(a, off, 64);
        if (l == i) lout = Svd - 2.0f * a;
      }
      if (l < 16) l_sl[w * 16 + l] = lout;
    }
    __syncthreads();  // (1) l_sl ready

    // ---- B2+B3: waves 0-7 redundant softmax, then role split ----
    if (w < 8) {
      float v0 = l_sl[l], v1 = l_sl[64 + l], v2 = l_sl[128 + l], v3 = l_sl[192 + l];
      float mx = fmaxf(fmaxf(v0, v1), fmaxf(v2, v3));
      #pragma unroll
      for (int off = 32; off > 0; off >>= 1) mx = fmaxf(mx, __shfl_xor(mx, off, 64));
      float e0 = __builtin_amdgcn_exp2f((v0 - mx) * LOG2E);
      float e1 = __builtin_amdgcn_exp2f((v1 - mx) * LOG2E);
      float e2 = __builtin_amdgcn_exp2f((v2 - mx) * LOG2E);
      float e3 = __builtin_amdgcn_exp2f((v3 - mx) * LOG2E);
      float sq = (e0 + e1) + (e2 + e3);
      float nq = fmaf(e0, wenc_l[l], fmaf(e1, wenc_l[64 + l],
                 fmaf(e2, wenc_l[128 + l], e3 * wenc_l[192 + l])));
      #pragma unroll
      for (int off = 32; off > 0; off >>= 1) {
        sq += __shfl_xor(sq, off, 64);
        nq += __shfl_xor(nq, off, 64);
      }
      float rden = __builtin_amdgcn_rcpf(sq);
      float yt = nq * rden + wtw512 * yin_l[t] + wtb0;

      if (tid < 256) {
        // gates+cell (threads 0-255); partials are f16 pairs in gph
        int h = tid, hb = h >> 1, sel = h & 1;
        float g0 = 0.0f, g1 = 0.0f, g2 = 0.0f, g3 = 0.0f;
        #pragma unroll
        for (int s = 0; s < 8; ++s) {
          const u32* gs = gph + s * 512;
          g0 += unpk(gs[hb], sel);
          g1 += unpk(gs[128 + hb], sel);
          g2 += unpk(gs[256 + hb], sel);
          g3 += unpk(gs[384 + hb], sel);
        }
        float gi = sigmoid_fast(g0 + yt * wih_l[h]       + bb_l[h]);
        float gf = sigmoid_fast(g1 + yt * wih_l[256 + h] + bb_l[256 + h]);
        float gg = tanh_fast   (g2 + yt * wih_l[512 + h] + bb_l[512 + h]);
        float go = sigmoid_fast(g3 + yt * wih_l[768 + h] + bb_l[768 + h]);
        float sn = gf * s_reg + gi * gg;
        s_reg = sn;
        float dn = go * tanh_fast(sn);
        float dn1 = __shfl_xor(dn, 1, 64);
        float sn1 = __shfl_xor(sn, 1, 64);
        if (sel == 0) {
          pk_ds[hb] = pkrtz(dn, dn1);
          pk_ds[128 + hb] = pkrtz(sn, sn1);
        }
      } else {
        // beta accumulation (waves 4-7): own e for te = (w-4)*64 + l
        float e_own = (w == 4) ? e0 : (w == 5) ? e1 : (w == 6) ? e2 : e3;
        bacc = fmaf(e_own, rden, bacc);
      }
    }
    __syncthreads();  // (2) pk_ds ready

    // ---- B4: waves 0-7: Wd GEMV (x1 for t+1) | waves 8-15: Whh GEMV ----
    if (w < 8) {
      float a0 = 0, a1 = 0, a2 = 0, a3 = 0, a4 = 0, a5 = 0, a6 = 0, a7 = 0;
      const u32* base = wdt2 + (size_t)(w * 32) * 512 + l * 8;
      const u32* pk = (const u32*)pk_ds + w * 32;
      #pragma unroll 8
      for (int kk = 0; kk < 32; ++kk) {
        u32x4 W0 = *(const u32x4*)(base + (size_t)kk * 512);
        u32x4 W1 = *(const u32x4*)(base + (size_t)kk * 512 + 4);
        f16x2 dk = u2h2(pk[kk]);
        a0 = FDOT2(u2h2(W0[0]), dk, a0);
        a1 = FDOT2(u2h2(W0[1]), dk, a1);
        a2 = FDOT2(u2h2(W0[2]), dk, a2);
        a3 = FDOT2(u2h2(W0[3]), dk, a3);
        a4 = FDOT2(u2h2(W1[0]), dk, a4);
        a5 = FDOT2(u2h2(W1[1]), dk, a5);
        a6 = FDOT2(u2h2(W1[2]), dk, a6);
        a7 = FDOT2(u2h2(W1[3]), dk, a7);
      }
      u32* dst = x1ph + w * 256 + l * 4;
      dst[0] = pkrtz(a0, a1);
      dst[1] = pkrtz(a2, a3);
      dst[2] = pkrtz(a4, a5);
      dst[3] = pkrtz(a6, a7);
    } else {
      const int sl = w - 8;
      float a0 = 0, a1 = 0, a2 = 0, a3 = 0, a4 = 0, a5 = 0, a6 = 0, a7 = 0;
      float c0 = 0, c1 = 0, c2 = 0, c3 = 0, c4 = 0, c5 = 0, c6 = 0, c7 = 0;
      const u32* base = whht2 + (size_t)(sl * 16) * 1024 + l * 8;
      const u32* pk = (const u32*)pk_ds + sl * 16;
      #pragma unroll 4
      for (int kk = 0; kk < 16; ++kk) {
        u32x4 Wa0 = *(const u32x4*)(base + (size_t)kk * 1024);
        u32x4 Wa1 = *(const u32x4*)(base + (size_t)kk * 1024 + 4);
        u32x4 Wc0 = *(const u32x4*)(base + (size_t)kk * 1024 + 512);
        u32x4 Wc1 = *(const u32x4*)(base + (size_t)kk * 1024 + 516);
        f16x2 dk = u2h2(pk[kk]);
        a0 = FDOT2(u2h2(Wa0[0]), dk, a0);
        a1 = FDOT2(u2h2(Wa0[1]), dk, a1);
        a2 = FDOT2(u2h2(Wa0[2]), dk, a2);
        a3 = FDOT2(u2h2(Wa0[3]), dk, a3);
        a4 = FDOT2(u2h2(Wa1[0]), dk, a4);
        a5 = FDOT2(u2h2(Wa1[1]), dk, a5);
        a6 = FDOT2(u2h2(Wa1[2]), dk, a6);
        a7 = FDOT2(u2h2(Wa1[3]), dk, a7);
        c0 = FDOT2(u2h2(Wc0[0]), dk, c0);
        c1 = FDOT2(u2h2(Wc0[1]), dk, c1);
        c2 = FDOT2(u2h2(Wc0[2]), dk, c2);
        c3 = FDOT2(u2h2(Wc0[3]), dk, c3);
        c4 = FDOT2(u2h2(Wc1[0]), dk, c4);
        c5 = FDOT2(u2h2(Wc1[1]), dk, c5);
        c6 = FDOT2(u2h2(Wc1[2]), dk, c6);
        c7 = FDOT2(u2h2(Wc1[3]), dk, c7);
      }
      u32* dst = gph + sl * 512 + l * 4;
      dst[0] = pkrtz(a0, a1);
      dst[1] = pkrtz(a2, a3);
      dst[2] = pkrtz(a4, a5);
      dst[3] = pkrtz(a6, a7);
      u32* dst2 = gph + sl * 512 + 256 + l * 4;
      dst2[0] = pkrtz(c0, c1);
      dst2[1] = pkrtz(c2, c3);
      dst2[2] = pkrtz(c4, c5);
      dst2[3] = pkrtz(c6, c7);
    }
    __syncthreads();  // (3) x1ph, gph ready

    // ---- B5: assemble x1 for t+1 (threads 0-511) from f16 partials ----
    if (tid < 512) {
      int m = tid, mb = m >> 1, sel = m & 1;
      float s = 0.0f;
      #pragma unroll
      for (int sI = 0; sI < 8; ++sI) s += unpk(x1ph[sI * 256 + mb], sel);
      x1_l2[(m & 7) * 64 + (m >> 3)] = K2 * (wdb_l[m] + s);
    }
    __syncthreads();  // (4) x1_l2 ready
  }

  if (w >= 4 && w < 8) gbeta[b * NT + (w - 4) * 64 + l] = bacc;
}

extern "C" void kernel_launch(void* const* d_in, const int* in_sizes, int n_in,
                              void* d_out, int out_size, void* d_ws, size_t ws_size,
                              hipStream_t stream) {
  const float* enc  = (const float*)d_in[0];
  const float* yin  = (const float*)d_in[1];
  const float* Wd_w = (const float*)d_in[2];
  const float* Wd_b = (const float*)d_in[3];
  const float* Ud_w = (const float*)d_in[4];
  const float* vd_w = (const float*)d_in[5];
  const float* wt_w = (const float*)d_in[6];
  const float* wt_b = (const float*)d_in[7];
  const float* Wih  = (const float*)d_in[8];
  const float* Whh  = (const float*)d_in[9];
  const float* bih  = (const float*)d_in[10];
  const float* bhh  = (const float*)d_in[11];

  char* ws = (char*)d_ws;
  u16*   y1bf   = (u16*)(ws);                     // 16,777,216
  u16*   encbf  = (u16*)(ws + 16777216);          // 16,777,216
  u16*   udbf   = (u16*)(ws + 33554432);          // 524,288
  u32*   wdt2   = (u32*)(ws + 34078720);          // 524,288
  u32*   whht2  = (u32*)(ws + 34603008);          // 524,288
  float* gwenc  = (float*)(ws + 35127296);        // 65,536
  float* gbeta  = (float*)(ws + 35192832);        // 65,536

  convert_f32_bf16<<<8388608 / 256, 256, 0, stream>>>(enc, encbf, 8388608);
  convert_f32_bf16<<<262144 / 256, 256, 0, stream>>>(Ud_w, udbf, 262144);
  pack_wd2<<<512, 256, 0, stream>>>(Wd_w, wdt2);
  pack_whh2<<<512, 256, 0, stream>>>(Whh, whht2);
  gemm_y1<<<dim3(256, 8), 256, 0, stream>>>(encbf, udbf, y1bf);
  wenc_kernel<<<64, 256, 0, stream>>>(encbf, wt_w, gwenc);

  hipFuncSetAttribute((const void*)attn_scan,
                      hipFuncAttributeMaxDynamicSharedMemorySize, 90112);
  attn_scan<<<64, 1024, 90112, stream>>>(y1bf, wdt2, whht2, Wd_b, vd_w,
                                         wt_w, wt_b, Wih, bih, bhh, yin, gwenc,
                                         gbeta);
  bsum_kernel<<<64, 512, 0, stream>>>(encbf, gbeta, (float*)d_out);
}

// Round 13
// 4676.005 us; speedup vs baseline: 1.2111x; 1.1156x over previous
//
#include <hip/hip_runtime.h>

typedef unsigned short u16;
typedef unsigned int u32;
typedef __attribute__((ext_vector_type(8))) short short8v;
typedef __attribute__((ext_vector_type(4))) float f32x4;
typedef __attribute__((ext_vector_type(4))) unsigned int u32x4;
typedef __attribute__((ext_vector_type(2))) _Float16 f16x2;

#define NB 64
#define NT 256
#define NM 512
#define NH 256

#define K2 2.8853900817779268f   // 2*log2(e)
#define LOG2E 1.4426950408889634f

__device__ __forceinline__ float bf2f(u16 u) {
  union { unsigned i; float f; } c; c.i = ((unsigned)u) << 16; return c.f;
}
__device__ __forceinline__ u16 f2bf(float f) {
  union { float fv; unsigned i; } c; c.fv = f;
  unsigned i = c.i;
  return (u16)((i + 0x7fffu + ((i >> 16) & 1u)) >> 16);
}
__device__ __forceinline__ float bits2f(u32 u) {
  union { unsigned i; float f; } c; c.i = u; return c.f;
}
__device__ __forceinline__ f16x2 u2h2(u32 u) {
  union { u32 i; f16x2 h; } c; c.i = u; return c.h;
}
// pack two floats to f16x2 bits (cvt_pkrtz returns __fp16 vec; bit-cast via union)
__device__ __forceinline__ u32 pkrtz(float a, float b) {
  auto h = __builtin_amdgcn_cvt_pkrtz(a, b);
  union { decltype(h) v; u32 i; } c; c.v = h; return c.i;
}
// unpack one f16 of a pair to float
__device__ __forceinline__ float unpk(u32 v, int hi) {
  f16x2 h = u2h2(v);
  return hi ? (float)h.y : (float)h.x;
}
#if __has_builtin(__builtin_amdgcn_fdot2)
__device__ __forceinline__ float FDOT2(f16x2 a, f16x2 b, float c) {
  return __builtin_amdgcn_fdot2(a, b, c, false);
}
#else
__device__ __forceinline__ float FDOT2(f16x2 a, f16x2 b, float c) {
  c = fmaf((float)a.x, (float)b.x, c);
  return fmaf((float)a.y, (float)b.y, c);
}
#endif
__device__ __forceinline__ float tanh_fast(float x) {
  return 1.0f - 2.0f * __builtin_amdgcn_rcpf(1.0f + __builtin_amdgcn_exp2f(K2 * x));
}
__device__ __forceinline__ float sigmoid_fast(float x) {
  return __builtin_amdgcn_rcpf(1.0f + __builtin_amdgcn_exp2f(-LOG2E * x));
}

__global__ void convert_f32_bf16(const float* __restrict__ in, u16* __restrict__ out, int n) {
  int i = blockIdx.x * blockDim.x + threadIdx.x;
  if (i < n) out[i] = f2bf(in[i]);
}

// wdt2[k2*512+m] = pack_f16(Wd_w[m][2k2], Wd_w[m][2k2+1]);  k2 in [0,256)
__global__ __launch_bounds__(256) void pack_wd2(const float* __restrict__ in,
                                                u32* __restrict__ out) {
  int i = blockIdx.x * 256 + threadIdx.x;   // 131072
  int k2 = i >> 9, m = i & 511;
  out[i] = pkrtz(in[m * 512 + 2 * k2], in[m * 512 + 2 * k2 + 1]);
}
// whht2[k2*1024+r] = pack_f16(Whh[r][2k2], Whh[r][2k2+1]);  k2 in [0,128)
__global__ __launch_bounds__(256) void pack_whh2(const float* __restrict__ in,
                                                 u32* __restrict__ out) {
  int i = blockIdx.x * 256 + threadIdx.x;   // 131072
  int k2 = i >> 10, r = i & 1023;
  out[i] = pkrtz(in[r * 256 + 2 * k2], in[r * 256 + 2 * k2 + 1]);
}

// y1' = K2 * enc @ Ud^T  (bf16 out, prescaled for exp2-based tanh)
__global__ __launch_bounds__(256) void gemm_y1(const u16* __restrict__ A,
                                               const u16* __restrict__ Bm,
                                               u16* __restrict__ C) {
  const int w = threadIdx.x >> 6;
  const int l = threadIdx.x & 63;
  const int kg = l >> 4;
  const int r16 = l & 15;
  const int rowbase = blockIdx.x * 64 + w * 16;
  const int colbase = blockIdx.y * 64;
  const u16* ap = A + (size_t)(rowbase + r16) * 512 + kg * 8;
  f32x4 acc0 = {0,0,0,0}, acc1 = {0,0,0,0}, acc2 = {0,0,0,0}, acc3 = {0,0,0,0};
  for (int k = 0; k < 512; k += 32) {
    short8v af = *(const short8v*)(ap + k);
    const u16* bp = Bm + (size_t)(colbase + r16) * 512 + kg * 8 + k;
    short8v b0 = *(const short8v*)(bp);
    short8v b1 = *(const short8v*)(bp + 16 * 512);
    short8v b2 = *(const short8v*)(bp + 32 * 512);
    short8v b3 = *(const short8v*)(bp + 48 * 512);
    acc0 = __builtin_amdgcn_mfma_f32_16x16x32_bf16(af, b0, acc0, 0, 0, 0);
    acc1 = __builtin_amdgcn_mfma_f32_16x16x32_bf16(af, b1, acc1, 0, 0, 0);
    acc2 = __builtin_amdgcn_mfma_f32_16x16x32_bf16(af, b2, acc2, 0, 0, 0);
    acc3 = __builtin_amdgcn_mfma_f32_16x16x32_bf16(af, b3, acc3, 0, 0, 0);
  }
  #pragma unroll
  for (int j = 0; j < 4; ++j) {
    int r = rowbase + (l >> 4) * 4 + j;
    C[(size_t)r * 512 + colbase +  0 + r16] = f2bf(K2 * acc0[j]);
    C[(size_t)r * 512 + colbase + 16 + r16] = f2bf(K2 * acc1[j]);
    C[(size_t)r * 512 + colbase + 32 + r16] = f2bf(K2 * acc2[j]);
    C[(size_t)r * 512 + colbase + 48 + r16] = f2bf(K2 * acc3[j]);
  }
}

// w_enc[b,te] = sum_m enc[b,te,m] * wtw[m]
__global__ __launch_bounds__(256) void wenc_kernel(const u16* __restrict__ encbf,
                                                   const float* __restrict__ wtw,
                                                   float* __restrict__ gwenc) {
  int b = blockIdx.x, te = threadIdx.x;
  const u16* ep = encbf + ((size_t)(b * NT + te)) * NM;
  float a = 0.0f;
  for (int c8 = 0; c8 < 64; ++c8) {
    short8v v = *(const short8v*)(ep + c8 * 8);
    #pragma unroll
    for (int jj = 0; jj < 8; ++jj) a = fmaf(bf2f((u16)v[jj]), wtw[c8 * 8 + jj], a);
  }
  gwenc[b * NT + te] = a;
}

// out[b,m] = sum_te betaAcc[b,te] * enc[b,te,m]
__global__ __launch_bounds__(512) void bsum_kernel(const u16* __restrict__ encbf,
                                                   const float* __restrict__ gbeta,
                                                   float* __restrict__ out) {
  __shared__ float bl[NT];
  int b = blockIdx.x, m = threadIdx.x;
  if (m < 256) bl[m] = gbeta[b * NT + m];
  __syncthreads();
  const u16* ep = encbf + (size_t)b * NT * NM + m;
  float a = 0.0f;
  #pragma unroll 8
  for (int te = 0; te < NT; ++te)
    a = fmaf(bf2f(ep[(size_t)te * NM]), bl[te], a);
  out[b * NM + m] = a;
}

// ONE workgroup per batch, designed for the compiler's 64-VGPR budget:
// no register tiles; y1 streamed from L2 each step (t-rotated index defeats
// LICM hoisting); every phase uses all/most waves (latency balance).
__global__ void __launch_bounds__(1024) attn_scan(
    const u16* __restrict__ y1bf,    // [B,T,M] prescaled by K2
    const u32* __restrict__ wdt2,    // [256 k2][512 m] f16-pairs along k of (d;s)
    const u32* __restrict__ whht2,   // [128 k2][1024 r] f16-pairs along k of d
    const float* __restrict__ Wd_b,  // [512]
    const float* __restrict__ vd,    // [512]
    const float* __restrict__ wtw,   // [513]
    const float* __restrict__ wtb,   // [1]
    const float* __restrict__ Wih,   // [1024]
    const float* __restrict__ bih,   // [1024]
    const float* __restrict__ bhh,   // [1024]
    const float* __restrict__ yin,   // [B,T]
    const float* __restrict__ gwenc, // [B,256]
    float* __restrict__ gbeta)       // [B,256] sum_t beta
{
  extern __shared__ char ldsraw[];
  u32* gph    = (u32*)ldsraw;              // [8][512] f16-pair Whh partials, 16 KiB
  u32* x1ph   = (u32*)(ldsraw + 16384);    // [8][256] f16-pair Wd partials, 8 KiB
  float* gact = (float*)(ldsraw + 24576);  // [1024] gate activations, 4 KiB

  __shared__ float x1_l2[NM];   // [j][m>>3]: idx (m&7)*64+(m>>3) holds x1[m]
  __shared__ u32 pk_ds[256];    // f16 pairs: [0..127]=d, [128..255]=s
  __shared__ float l_sl[NT];
  __shared__ float wih_l[1024];
  __shared__ float bb_l[1024];
  __shared__ float wenc_l[NT];
  __shared__ float yin_l[NT];
  __shared__ float wdb_l[NM];

  const int tid = threadIdx.x;
  const int b = blockIdx.x;
  const int w = tid >> 6, l = tid & 63;

  // ---- one-time init ----
  wih_l[tid] = Wih[tid];
  bb_l[tid] = bih[tid] + bhh[tid];
  if (tid < 256) {
    wenc_l[tid] = gwenc[b * NT + tid];
    yin_l[tid] = yin[b * NT + tid];
  }
  if (tid < 512) {
    float wb = Wd_b[tid];
    wdb_l[tid] = wb;
    x1_l2[(tid & 7) * 64 + (tid >> 3)] = K2 * wb;  // x1_0 = Wd·0 + b
  }
  for (int i = tid; i < 4096; i += 1024) gph[i] = 0;  // Whh·d_{-1} = 0

  float vr[8];
  #pragma unroll
  for (int j = 0; j < 8; ++j) vr[j] = vd[l * 8 + j];
  float sv = 0.0f;
  #pragma unroll
  for (int j = 0; j < 8; ++j) sv += vr[j];
  #pragma unroll
  for (int off = 32; off > 0; off >>= 1) sv += __shfl_xor(sv, off, 64);
  const float Svd = sv;
  const float wtw512 = wtw[NM];
  const float wtb0 = wtb[0];

  const u16* ybase = y1bf + ((size_t)(b * NT + w * 16) << 9) + l * 8;

  float s_reg = 0.0f;  // threads 0-255: cell state c[h]
  float bacc = 0.0f;   // waves 4-7: sum_t beta[(w-4)*64+l]
  __syncthreads();

  #pragma unroll 1
  for (int t = 0; t < NT; ++t) {
    // ---- B1: l_it (all 16 waves, 16 te each; y1 streamed from L2).
    // Row order rotates with t so addresses are t-dependent -> LICM can't
    // hoist the loads into a (spilled) cross-iteration tile.
    {
      float xr[8];
      #pragma unroll
      for (int j = 0; j < 8; ++j) xr[j] = x1_l2[j * 64 + l];
      float lout = 0.0f;
      #pragma unroll
      for (int i = 0; i < 16; ++i) {
        const int ii = (i + t) & 15;
        u32x4 V = *(const u32x4*)(ybase + ((size_t)ii << 9));
        float a = 0.0f;
        #pragma unroll
        for (int n = 0; n < 4; ++n) {
          u32 v = V[n];
          float e0 = __builtin_amdgcn_exp2f(xr[2 * n] + bits2f(v << 16));
          a = fmaf(vr[2 * n], __builtin_amdgcn_rcpf(1.0f + e0), a);
          float e1 = __builtin_amdgcn_exp2f(xr[2 * n + 1] + bits2f(v & 0xffff0000u));
          a = fmaf(vr[2 * n + 1], __builtin_amdgcn_rcpf(1.0f + e1), a);
        }
        #pragma unroll
        for (int off = 32; off > 0; off >>= 1) a += __shfl_xor(a, off, 64);
        if (l == ii) lout = Svd - 2.0f * a;
      }
      if (l < 16) l_sl[w * 16 + l] = lout;
    }
    __syncthreads();  // (1) l_sl ready

    // ---- B2: softmax redundantly in ALL 16 waves (no idle waves) ----
    float yt, rden, e0, e1, e2, e3;
    {
      float v0 = l_sl[l], v1 = l_sl[64 + l], v2 = l_sl[128 + l], v3 = l_sl[192 + l];
      float mx = fmaxf(fmaxf(v0, v1), fmaxf(v2, v3));
      #pragma unroll
      for (int off = 32; off > 0; off >>= 1) mx = fmaxf(mx, __shfl_xor(mx, off, 64));
      e0 = __builtin_amdgcn_exp2f((v0 - mx) * LOG2E);
      e1 = __builtin_amdgcn_exp2f((v1 - mx) * LOG2E);
      e2 = __builtin_amdgcn_exp2f((v2 - mx) * LOG2E);
      e3 = __builtin_amdgcn_exp2f((v3 - mx) * LOG2E);
      float sq = (e0 + e1) + (e2 + e3);
      float nq = fmaf(e0, wenc_l[l], fmaf(e1, wenc_l[64 + l],
                 fmaf(e2, wenc_l[128 + l], e3 * wenc_l[192 + l])));
      #pragma unroll
      for (int off = 32; off > 0; off >>= 1) {
        sq += __shfl_xor(sq, off, 64);
        nq += __shfl_xor(nq, off, 64);
      }
      rden = __builtin_amdgcn_rcpf(sq);
      yt = nq * rden + wtw512 * yin_l[t] + wtb0;
    }
    // beta accumulation (waves 4-7 own te slices; others skip - tiny)
    if (w >= 4 && w < 8) {
      float e_own = (w == 4) ? e0 : (w == 5) ? e1 : (w == 6) ? e2 : e3;
      bacc = fmaf(e_own, rden, bacc);
    }

    // ---- B3a: gate activations, one row per thread (all 1024 threads) ----
    {
      int r = tid, hb = r >> 1, sel = r & 1;
      float g = 0.0f;
      #pragma unroll
      for (int s = 0; s < 8; ++s) g += unpk(gph[s * 512 + hb], sel);
      float pre = g + yt * wih_l[r] + bb_l[r];
      float act = (r >= 512 && r < 768) ? tanh_fast(pre) : sigmoid_fast(pre);
      gact[r] = act;
    }
    __syncthreads();  // (2) gact ready

    // ---- B3b: cell update (threads 0-255) ----
    if (tid < 256) {
      int h = tid, hb = h >> 1, sel = h & 1;
      float gi = gact[h];
      float gf = gact[256 + h];
      float gg = gact[512 + h];
      float go = gact[768 + h];
      float sn = gf * s_reg + gi * gg;
      s_reg = sn;
      float dn = go * tanh_fast(sn);
      float dn1 = __shfl_xor(dn, 1, 64);
      float sn1 = __shfl_xor(sn, 1, 64);
      if (sel == 0) {
        pk_ds[hb] = pkrtz(dn, dn1);
        pk_ds[128 + hb] = pkrtz(sn, sn1);
      }
    }
    __syncthreads();  // (3) pk_ds ready

    // ---- B4: waves 0-7: Wd GEMV (x1 for t+1) | waves 8-15: Whh GEMV ----
    if (w < 8) {
      float a0 = 0, a1 = 0, a2 = 0, a3 = 0, a4 = 0, a5 = 0, a6 = 0, a7 = 0;
      const u32* base = wdt2 + (size_t)(w * 32) * 512 + l * 8;
      const u32* pk = (const u32*)pk_ds + w * 32;
      #pragma unroll 8
      for (int kk = 0; kk < 32; ++kk) {
        u32x4 W0 = *(const u32x4*)(base + (size_t)kk * 512);
        u32x4 W1 = *(const u32x4*)(base + (size_t)kk * 512 + 4);
        f16x2 dk = u2h2(pk[kk]);
        a0 = FDOT2(u2h2(W0[0]), dk, a0);
        a1 = FDOT2(u2h2(W0[1]), dk, a1);
        a2 = FDOT2(u2h2(W0[2]), dk, a2);
        a3 = FDOT2(u2h2(W0[3]), dk, a3);
        a4 = FDOT2(u2h2(W1[0]), dk, a4);
        a5 = FDOT2(u2h2(W1[1]), dk, a5);
        a6 = FDOT2(u2h2(W1[2]), dk, a6);
        a7 = FDOT2(u2h2(W1[3]), dk, a7);
      }
      u32* dst = x1ph + w * 256 + l * 4;
      dst[0] = pkrtz(a0, a1);
      dst[1] = pkrtz(a2, a3);
      dst[2] = pkrtz(a4, a5);
      dst[3] = pkrtz(a6, a7);
    } else {
      const int sl = w - 8;
      float a0 = 0, a1 = 0, a2 = 0, a3 = 0, a4 = 0, a5 = 0, a6 = 0, a7 = 0;
      float c0 = 0, c1 = 0, c2 = 0, c3 = 0, c4 = 0, c5 = 0, c6 = 0, c7 = 0;
      const u32* base = whht2 + (size_t)(sl * 16) * 1024 + l * 8;
      const u32* pk = (const u32*)pk_ds + sl * 16;
      #pragma unroll 4
      for (int kk = 0; kk < 16; ++kk) {
        u32x4 Wa0 = *(const u32x4*)(base + (size_t)kk * 1024);
        u32x4 Wa1 = *(const u32x4*)(base + (size_t)kk * 1024 + 4);
        u32x4 Wc0 = *(const u32x4*)(base + (size_t)kk * 1024 + 512);
        u32x4 Wc1 = *(const u32x4*)(base + (size_t)kk * 1024 + 516);
        f16x2 dk = u2h2(pk[kk]);
        a0 = FDOT2(u2h2(Wa0[0]), dk, a0);
        a1 = FDOT2(u2h2(Wa0[1]), dk, a1);
        a2 = FDOT2(u2h2(Wa0[2]), dk, a2);
        a3 = FDOT2(u2h2(Wa0[3]), dk, a3);
        a4 = FDOT2(u2h2(Wa1[0]), dk, a4);
        a5 = FDOT2(u2h2(Wa1[1]), dk, a5);
        a6 = FDOT2(u2h2(Wa1[2]), dk, a6);
        a7 = FDOT2(u2h2(Wa1[3]), dk, a7);
        c0 = FDOT2(u2h2(Wc0[0]), dk, c0);
        c1 = FDOT2(u2h2(Wc0[1]), dk, c1);
        c2 = FDOT2(u2h2(Wc0[2]), dk, c2);
        c3 = FDOT2(u2h2(Wc0[3]), dk, c3);
        c4 = FDOT2(u2h2(Wc1[0]), dk, c4);
        c5 = FDOT2(u2h2(Wc1[1]), dk, c5);
        c6 = FDOT2(u2h2(Wc1[2]), dk, c6);
        c7 = FDOT2(u2h2(Wc1[3]), dk, c7);
      }
      u32* dst = gph + sl * 512 + l * 4;
      dst[0] = pkrtz(a0, a1);
      dst[1] = pkrtz(a2, a3);
      dst[2] = pkrtz(a4, a5);
      dst[3] = pkrtz(a6, a7);
      u32* dst2 = gph + sl * 512 + 256 + l * 4;
      dst2[0] = pkrtz(c0, c1);
      dst2[1] = pkrtz(c2, c3);
      dst2[2] = pkrtz(c4, c5);
      dst2[3] = pkrtz(c6, c7);
    }
    __syncthreads();  // (4) x1ph, gph ready

    // ---- B5: assemble x1 for t+1 (threads 0-511) from f16 partials ----
    if (tid < 512) {
      int m = tid, mb = m >> 1, sel = m & 1;
      float s = 0.0f;
      #pragma unroll
      for (int sI = 0; sI < 8; ++sI) s += unpk(x1ph[sI * 256 + mb], sel);
      x1_l2[(m & 7) * 64 + (m >> 3)] = K2 * (wdb_l[m] + s);
    }
    __syncthreads();  // (5) x1_l2 ready
  }

  if (w >= 4 && w < 8) gbeta[b * NT + (w - 4) * 64 + l] = bacc;
}

extern "C" void kernel_launch(void* const* d_in, const int* in_sizes, int n_in,
                              void* d_out, int out_size, void* d_ws, size_t ws_size,
                              hipStream_t stream) {
  const float* enc  = (const float*)d_in[0];
  const float* yin  = (const float*)d_in[1];
  const float* Wd_w = (const float*)d_in[2];
  const float* Wd_b = (const float*)d_in[3];
  const float* Ud_w = (const float*)d_in[4];
  const float* vd_w = (const float*)d_in[5];
  const float* wt_w = (const float*)d_in[6];
  const float* wt_b = (const float*)d_in[7];
  const float* Wih  = (const float*)d_in[8];
  const float* Whh  = (const float*)d_in[9];
  const float* bih  = (const float*)d_in[10];
  const float* bhh  = (const float*)d_in[11];

  char* ws = (char*)d_ws;
  u16*   y1bf   = (u16*)(ws);                     // 16,777,216
  u16*   encbf  = (u16*)(ws + 16777216);          // 16,777,216
  u16*   udbf   = (u16*)(ws + 33554432);          // 524,288
  u32*   wdt2   = (u32*)(ws + 34078720);          // 524,288
  u32*   whht2  = (u32*)(ws + 34603008);          // 524,288
  float* gwenc  = (float*)(ws + 35127296);        // 65,536
  float* gbeta  = (float*)(ws + 35192832);        // 65,536

  convert_f32_bf16<<<8388608 / 256, 256, 0, stream>>>(enc, encbf, 8388608);
  convert_f32_bf16<<<262144 / 256, 256, 0, stream>>>(Ud_w, udbf, 262144);
  pack_wd2<<<512, 256, 0, stream>>>(Wd_w, wdt2);
  pack_whh2<<<512, 256, 0, stream>>>(Whh, whht2);
  gemm_y1<<<dim3(256, 8), 256, 0, stream>>>(encbf, udbf, y1bf);
  wenc_kernel<<<64, 256, 0, stream>>>(encbf, wt_w, gwenc);

  hipFuncSetAttribute((const void*)attn_scan,
                      hipFuncAttributeMaxDynamicSharedMemorySize, 28672);
  attn_scan<<<64, 1024, 28672, stream>>>(y1bf, wdt2, whht2, Wd_b, vd_w,
                                         wt_w, wt_b, Wih, bih, bhh, yin, gwenc,
                                         gbeta);
  bsum_kernel<<<64, 512, 0, stream>>>(encbf, gbeta, (float*)d_out);
}